// Round 1
// baseline (445.673 us; speedup 1.0000x reference)
//
#include <hip/hip_runtime.h>
#include <math.h>

#define N 512
#define H 12
#define CC 16      // C
#define CZ 128
#define CS 384
#define PQ 4
#define PV 8
#define CATR 2017

// ---------------------------------------------------------------------------
// Kernel 1: all projections. out[o,n] = sum_c W_sel[o][c] * s[c,n], o in [0,1152)
// proj rows: q:0..191 (c*12+h), k:192.., v:384.., qp:576.. (d*48+h*4+p),
//            kp:720.., vp:864.. (d*96+h*8+p)
// grid (72, 4): o-tile 16, n-tile 128. block 256.
// ---------------------------------------------------------------------------
__global__ __launch_bounds__(256) void k_proj(
    const float* __restrict__ s,
    const float* __restrict__ Wq, const float* __restrict__ Wk, const float* __restrict__ Wv,
    const float* __restrict__ Wqp, const float* __restrict__ Wkp, const float* __restrict__ Wvp,
    float* __restrict__ proj)
{
    __shared__ float Wt[16][33];
    __shared__ float St[32][128];
    int t = threadIdx.x;
    int o0 = blockIdx.x * 16;
    int n0 = blockIdx.y * 128;
    const float* Wsrc; int orow;
    if (o0 < 192)      { Wsrc = Wq;  orow = o0; }
    else if (o0 < 384) { Wsrc = Wk;  orow = o0-192; }
    else if (o0 < 576) { Wsrc = Wv;  orow = o0-384; }
    else if (o0 < 720) { Wsrc = Wqp; orow = o0-576; }
    else if (o0 < 864) { Wsrc = Wkp; orow = o0-720; }
    else               { Wsrc = Wvp; orow = o0-864; }

    int og = t >> 6, nl = t & 63;
    float acc[4][2] = {};
    for (int c0 = 0; c0 < CS; c0 += 32) {
        __syncthreads();
        for (int k = 0; k < 2; k++) {           // W tile 16x32
            int idx = t + k*256;
            int oo = idx >> 5, ccol = idx & 31;
            Wt[oo][ccol] = Wsrc[(orow+oo)*CS + c0 + ccol];
        }
        for (int k = 0; k < 4; k++) {           // s tile 32x128 (float4)
            int idx = t + k*256;
            int ccr = idx >> 5, nn4 = idx & 31;
            float4 v = *(const float4*)&s[(c0+ccr)*N + n0 + nn4*4];
            *(float4*)&St[ccr][nn4*4] = v;
        }
        __syncthreads();
        for (int kk = 0; kk < 32; kk++) {
            float sv0 = St[kk][nl], sv1 = St[kk][nl+64];
            #pragma unroll
            for (int r = 0; r < 4; r++) {
                float w = Wt[og*4+r][kk];
                acc[r][0] += w * sv0;
                acc[r][1] += w * sv1;
            }
        }
    }
    for (int r = 0; r < 4; r++) {
        int o = o0 + og*4 + r;
        proj[o*N + n0 + nl]      = acc[r][0];
        proj[o*N + n0 + 64 + nl] = acc[r][1];
    }
}

// ---------------------------------------------------------------------------
// Kernel 2: apply frames. thread per (hp,n); hp<48: qp, <96: kp, else vp.
// ---------------------------------------------------------------------------
__global__ void k_frames(const float* __restrict__ proj,
                         const float* __restrict__ t_r, const float* __restrict__ t_t,
                         float* __restrict__ qg, float* __restrict__ kg, float* __restrict__ vg)
{
    int gid = blockIdx.x * blockDim.x + threadIdx.x;  // 192*512
    int n = gid & (N-1);
    int hp = gid >> 9;
    if (hp >= 192) return;
    const float* src; float* dst; int rowb, stride;
    if (hp < 48)      { src = proj + 576*N; dst = qg; rowb = hp;    stride = 48; }
    else if (hp < 96) { src = proj + 720*N; dst = kg; rowb = hp-48; stride = 48; }
    else              { src = proj + 864*N; dst = vg; rowb = hp-96; stride = 96; }
    float x0 = src[(rowb + 0*stride)*N + n];
    float x1 = src[(rowb + 1*stride)*N + n];
    float x2 = src[(rowb + 2*stride)*N + n];
    #pragma unroll
    for (int d = 0; d < 3; d++) {
        float r0 = t_r[(n*3+d)*3+0], r1 = t_r[(n*3+d)*3+1], r2 = t_r[(n*3+d)*3+2];
        dst[(rowb + d*stride)*N + n] = r0*x0 + r1*x1 + r2*x2 + t_t[n*3+d];
    }
}

// ---------------------------------------------------------------------------
// Kernel 2b: sq_q[h,n] = sum_{d,p} qg^2 ; sq_k likewise.
// ---------------------------------------------------------------------------
__global__ void k_sq(const float* __restrict__ qg, const float* __restrict__ kg,
                     float* __restrict__ sq_q, float* __restrict__ sq_k)
{
    int gid = blockIdx.x * blockDim.x + threadIdx.x;  // 2*12*512
    int n = gid & (N-1);
    int sel = gid >> 9;
    int h = sel % H;
    const float* g = (sel < H) ? qg : kg;
    float* outp = (sel < H) ? sq_q : sq_k;
    float acc = 0.f;
    #pragma unroll
    for (int d = 0; d < 3; d++)
        #pragma unroll
        for (int p = 0; p < PQ; p++) {
            float v = g[(size_t)((d*H + h)*PQ + p)*N + n];
            acc += v*v;
        }
    outp[h*N + n] = acc;
}

// ---------------------------------------------------------------------------
// Kernel 3: logits + softmax, one block per i, 256 threads, 2 j per thread.
// logit = w_l*(0.25*qk + b_bias - ch*(sqq + sqk - 2*qg.kg)), ch = softplus(g)*w_c/2
// ---------------------------------------------------------------------------
__global__ __launch_bounds__(256) void k_attn(
    const float* __restrict__ z, const float* __restrict__ proj,
    const float* __restrict__ qg, const float* __restrict__ kg,
    const float* __restrict__ sq_q, const float* __restrict__ sq_k,
    const float* __restrict__ Wb, const float* __restrict__ gamma,
    float* __restrict__ a)
{
    int i = blockIdx.x;
    int t = threadIdx.x;
    int j0 = t*2;
    const float w_l  = 0.57735026918962584f;   // sqrt(1/3)
    const float w_c2 = 0.11785113019775793f;   // sqrt(1/18)/2

    float ch[H];
    #pragma unroll
    for (int h = 0; h < H; h++) {
        float g = gamma[h];
        float sp = (g > 20.f) ? g : log1pf(expf(g));
        ch[h] = sp * w_c2;
    }

    float acc[H][2] = {};
    const float* q = proj;
    const float* k = proj + 192*N;

    for (int c = 0; c < CZ; c++) {            // b_bias
        float2 zz = *(const float2*)&z[((size_t)c*N + i)*N + j0];
        #pragma unroll
        for (int h = 0; h < H; h++) {
            float w = Wb[h*CZ + c];
            acc[h][0] += w*zz.x; acc[h][1] += w*zz.y;
        }
    }
    for (int c = 0; c < CC; c++) {            // qk / 4
        #pragma unroll
        for (int h = 0; h < H; h++) {
            float qv = 0.25f * q[(size_t)(c*H+h)*N + i];
            float2 kk = *(const float2*)&k[(size_t)(c*H+h)*N + j0];
            acc[h][0] += qv*kk.x; acc[h][1] += qv*kk.y;
        }
    }
    for (int dp = 0; dp < 3*PQ; dp++) {       // +2*ch*(qg.kg)
        int d = dp >> 2, p = dp & 3;
        #pragma unroll
        for (int h = 0; h < H; h++) {
            int row = (d*H+h)*PQ + p;
            float qv = 2.f*ch[h]*qg[(size_t)row*N + i];
            float2 kk = *(const float2*)&kg[(size_t)row*N + j0];
            acc[h][0] += qv*kk.x; acc[h][1] += qv*kk.y;
        }
    }
    float logit[H][2];
    #pragma unroll
    for (int h = 0; h < H; h++) {
        float sqq = sq_q[h*N + i];
        float2 sk = *(const float2*)&sq_k[h*N + j0];
        logit[h][0] = w_l*(acc[h][0] - ch[h]*(sqq + sk.x));
        logit[h][1] = w_l*(acc[h][1] - ch[h]*(sqq + sk.y));
    }

    // softmax over 512 j for each of 12 h
    __shared__ float red[2][H][4];
    int wv = t >> 6, lane = t & 63;
    #pragma unroll
    for (int h = 0; h < H; h++) {
        float m = fmaxf(logit[h][0], logit[h][1]);
        for (int sft = 32; sft > 0; sft >>= 1) m = fmaxf(m, __shfl_xor(m, sft));
        if (lane == 0) red[0][h][wv] = m;
    }
    __syncthreads();
    #pragma unroll
    for (int h = 0; h < H; h++) {
        float m = fmaxf(fmaxf(red[0][h][0], red[0][h][1]), fmaxf(red[0][h][2], red[0][h][3]));
        float e0 = __expf(logit[h][0]-m), e1 = __expf(logit[h][1]-m);
        logit[h][0] = e0; logit[h][1] = e1;
        float sm = e0 + e1;
        for (int sft = 32; sft > 0; sft >>= 1) sm += __shfl_xor(sm, sft);
        if (lane == 0) red[1][h][wv] = sm;
    }
    __syncthreads();
    #pragma unroll
    for (int h = 0; h < H; h++) {
        float sm = red[1][h][0]+red[1][h][1]+red[1][h][2]+red[1][h][3];
        float inv = 1.f/sm;
        float2 o; o.x = logit[h][0]*inv; o.y = logit[h][1]*inv;
        *(float2*)&a[((size_t)h*N + i)*N + j0] = o;
    }
}

// ---------------------------------------------------------------------------
// Kernel 4: o1[(c,h),i] = sum_j a[h,i,j]*z[c,i,j]. block per i.
// thread owns (c-pair, h-triple). z transposed through LDS (pad 66), a staged (pad 516).
// ---------------------------------------------------------------------------
__global__ __launch_bounds__(256) void k_o1(
    const float* __restrict__ z, const float* __restrict__ a, float* __restrict__ cat)
{
    __shared__ float als[H*516];
    __shared__ float zls[128*66];
    int i = blockIdx.x;
    int t = threadIdx.x;
    int c0 = (t >> 2)*2;
    int h0 = (t & 3)*3;
    for (int k = 0; k < 6; k++) {              // stage a: 1536 float4
        int idx = t + k*256;
        int h = idx >> 7, j4 = idx & 127;
        float4 v = *(const float4*)&a[((size_t)h*N + i)*N + j4*4];
        *(float4*)&als[h*516 + j4*4] = v;
    }
    float acc[2][3] = {};
    for (int jc = 0; jc < 8; jc++) {
        __syncthreads();
        for (int k = 0; k < 16; k++) {         // stage z chunk 128x64 (float2)
            int idx = t + k*256;
            int c = idx >> 5, j2 = idx & 31;
            float2 v = *(const float2*)&z[((size_t)c*N + i)*N + jc*64 + j2*2];
            *(float2*)&zls[c*66 + j2*2] = v;
        }
        __syncthreads();
        for (int jj = 0; jj < 64; jj++) {
            float z0 = zls[c0*66 + jj], z1 = zls[(c0+1)*66 + jj];
            float a0 = als[h0*516 + jc*64 + jj];
            float a1 = als[(h0+1)*516 + jc*64 + jj];
            float a2 = als[(h0+2)*516 + jc*64 + jj];
            acc[0][0] += z0*a0; acc[0][1] += z0*a1; acc[0][2] += z0*a2;
            acc[1][0] += z1*a0; acc[1][1] += z1*a1; acc[1][2] += z1*a2;
        }
    }
    #pragma unroll
    for (int cc = 0; cc < 2; cc++)
        #pragma unroll
        for (int hh = 0; hh < 3; hh++)
            cat[(size_t)((c0+cc)*H + h0+hh)*N + i] = acc[cc][hh];
}

// ---------------------------------------------------------------------------
// Kernel 5: o2[(c,h),i] = sum_j a[h,i,j] v[c,h,j]; o3g[(e,h,p),i] = sum_j a*vg.
// block per (h, i-tile 32). 40 output rows (16 o2 + 24 o3g). 5 rows/thread.
// ---------------------------------------------------------------------------
__global__ __launch_bounds__(256) void k_o2o3g(
    const float* __restrict__ a, const float* __restrict__ proj, const float* __restrict__ vg,
    float* __restrict__ cat, float* __restrict__ o3g)
{
    __shared__ float ats[32*66];
    __shared__ float vts[40*66];
    int h = blockIdx.x, i0 = blockIdx.y*32;
    int t = threadIdx.x;
    int il = t & 31, rg = t >> 5;
    const float* v = proj + 384*N;
    float acc[5] = {};
    for (int jc = 0; jc < 8; jc++) {
        __syncthreads();
        for (int k = 0; k < 4; k++) {          // a tile 32x64 (float2)
            int idx = t + k*256;
            int ii = idx >> 5, j2 = idx & 31;
            *(float2*)&ats[ii*66 + j2*2] =
                *(const float2*)&a[((size_t)h*N + i0+ii)*N + jc*64 + j2*2];
        }
        for (int idx = t; idx < 1280; idx += 256) {  // v/vg tile 40x64 (float2)
            int r = idx >> 5, j2 = idx & 31;
            const float* src;
            if (r < 16) src = v + (size_t)(r*H + h)*N;
            else { int rr = r-16; int e = rr >> 3, p = rr & 7;
                   src = vg + (size_t)((e*H+h)*PV + p)*N; }
            *(float2*)&vts[r*66 + j2*2] = *(const float2*)&src[jc*64 + j2*2];
        }
        __syncthreads();
        for (int jj = 0; jj < 64; jj++) {
            float av = ats[il*66 + jj];
            #pragma unroll
            for (int r = 0; r < 5; r++)
                acc[r] += av * vts[(rg*5+r)*66 + jj];
        }
    }
    #pragma unroll
    for (int r = 0; r < 5; r++) {
        int row = rg*5 + r;
        if (row < 16) cat[(size_t)(1536 + row*H + h)*N + i0 + il] = acc[r];
        else { int rr = row-16; int e = rr >> 3, p = rr & 7;
               o3g[(size_t)((e*H+h)*PV + p)*N + i0 + il] = acc[r]; }
    }
}

// ---------------------------------------------------------------------------
// Kernel 6: o3[d,hp,i] = sum_e t_r[i,e,d]*(o3g[e,hp,i] - t_t[i,e])  -> cat rows 1728..
// ---------------------------------------------------------------------------
__global__ void k_o3(const float* __restrict__ o3g,
                     const float* __restrict__ t_r, const float* __restrict__ t_t,
                     float* __restrict__ cat)
{
    int gid = blockIdx.x*blockDim.x + threadIdx.x;  // 96*512
    int i = gid & (N-1), hp = gid >> 9;
    if (hp >= 96) return;
    float x0 = o3g[(size_t)(0*96 + hp)*N + i] - t_t[i*3+0];
    float x1 = o3g[(size_t)(1*96 + hp)*N + i] - t_t[i*3+1];
    float x2 = o3g[(size_t)(2*96 + hp)*N + i] - t_t[i*3+2];
    #pragma unroll
    for (int d = 0; d < 3; d++) {
        float o = t_r[(i*3+0)*3+d]*x0 + t_r[(i*3+1)*3+d]*x1 + t_r[(i*3+2)*3+d]*x2;
        cat[(size_t)(1728 + d*96 + hp)*N + i] = o;
    }
}

// ---------------------------------------------------------------------------
// Kernel 6b: o3_norm -> cat row 2016
// ---------------------------------------------------------------------------
__global__ void k_norm(float* __restrict__ cat)
{
    int i = blockIdx.x*blockDim.x + threadIdx.x;
    if (i >= N) return;
    float acc = 0.f;
    for (int r = 0; r < 288; r++) {
        float v = cat[(size_t)(1728+r)*N + i];
        acc += v*v;
    }
    cat[(size_t)2016*N + i] = sqrtf(acc);
}

// ---------------------------------------------------------------------------
// Kernel 7: out[o,n] = bs[o] + sum_c Ws[o,c]*cat[c,n]. split-K=4 with atomics.
// grid (24, 8, 4): o-tile 16, n-tile 64.
// ---------------------------------------------------------------------------
__global__ __launch_bounds__(256) void k_final(
    const float* __restrict__ Ws, const float* __restrict__ bs,
    const float* __restrict__ cat, float* __restrict__ out)
{
    __shared__ float Wt[16*33];
    __shared__ float Ct[32*66];
    int o0 = blockIdx.x*16, n0 = blockIdx.y*64;
    int ks = blockIdx.z;
    int kbeg = ks*505, kend = min(CATR, kbeg+505);
    int t = threadIdx.x;
    int og = t >> 6, nl = t & 63;
    float acc[4] = {};
    for (int c0 = kbeg; c0 < kend; c0 += 32) {
        __syncthreads();
        for (int k = 0; k < 2; k++) {          // W tile 16x32
            int idx = t + k*256;
            int oo = idx >> 5, ccol = idx & 31;
            int c = c0 + ccol;
            Wt[oo*33 + ccol] = (c < kend) ? Ws[(size_t)(o0+oo)*CATR + c] : 0.f;
        }
        for (int k = 0; k < 4; k++) {          // cat tile 32x64 (float2)
            int idx = t + k*256;
            int ccr = idx >> 5, j2 = idx & 31;
            int c = c0 + ccr;
            float2 vv; vv.x = 0.f; vv.y = 0.f;
            if (c < kend) vv = *(const float2*)&cat[(size_t)c*N + n0 + j2*2];
            *(float2*)&Ct[ccr*66 + j2*2] = vv;
        }
        __syncthreads();
        int klim = min(32, kend - c0);
        for (int kk = 0; kk < klim; kk++) {
            float cv = Ct[kk*66 + nl];
            #pragma unroll
            for (int r = 0; r < 4; r++)
                acc[r] += Wt[(og*4+r)*33 + kk] * cv;
        }
    }
    #pragma unroll
    for (int r = 0; r < 4; r++) {
        int o = o0 + og*4 + r;
        float val = acc[r];
        if (ks == 0) val += bs[o];
        atomicAdd(&out[(size_t)o*N + n0 + nl], val);
    }
}

// ---------------------------------------------------------------------------
extern "C" void kernel_launch(void* const* d_in, const int* in_sizes, int n_in,
                              void* d_out, int out_size, void* d_ws, size_t ws_size,
                              hipStream_t stream)
{
    const float* s     = (const float*)d_in[0];
    const float* z     = (const float*)d_in[1];
    const float* t_r   = (const float*)d_in[2];
    const float* t_t   = (const float*)d_in[3];
    const float* Wq    = (const float*)d_in[4];
    const float* Wk    = (const float*)d_in[5];
    const float* Wv    = (const float*)d_in[6];
    const float* Wqp   = (const float*)d_in[7];
    const float* Wkp   = (const float*)d_in[8];
    const float* Wvp   = (const float*)d_in[9];
    const float* Wb    = (const float*)d_in[10];
    const float* gamma = (const float*)d_in[11];
    const float* Ws    = (const float*)d_in[12];
    const float* bs    = (const float*)d_in[13];
    float* out = (float*)d_out;

    float* ws   = (float*)d_ws;
    float* proj = ws;                       // 1152*512
    float* qg   = proj + 1152*N;            // 144*512
    float* kg   = qg   + 144*N;             // 144*512
    float* vg   = kg   + 144*N;             // 288*512
    float* sq_q = vg   + 288*N;             // 12*512
    float* sq_k = sq_q + H*N;               // 12*512
    float* o3g  = sq_k + H*N;               // 288*512
    float* a    = o3g  + 288*N;             // 12*512*512
    float* cat  = a    + (size_t)H*N*N;     // 2017*512 (+ slack)

    k_proj  <<<dim3(72,4),  256, 0, stream>>>(s, Wq, Wk, Wv, Wqp, Wkp, Wvp, proj);
    k_frames<<<384,         256, 0, stream>>>(proj, t_r, t_t, qg, kg, vg);
    k_sq    <<<48,          256, 0, stream>>>(qg, kg, sq_q, sq_k);
    k_attn  <<<512,         256, 0, stream>>>(z, proj, qg, kg, sq_q, sq_k, Wb, gamma, a);
    k_o1    <<<512,         256, 0, stream>>>(z, a, cat);
    k_o2o3g <<<dim3(12,16), 256, 0, stream>>>(a, proj, vg, cat, o3g);
    k_o3    <<<192,         256, 0, stream>>>(o3g, t_r, t_t, cat);
    k_norm  <<<2,           256, 0, stream>>>(cat);
    hipMemsetAsync(out, 0, (size_t)CS*N*sizeof(float), stream);
    k_final <<<dim3(24,8,4),256, 0, stream>>>(Ws, bs, cat, out);
}

// Round 2
// 416.450 us; speedup vs baseline: 1.0702x; 1.0702x over previous
//
#include <hip/hip_runtime.h>
#include <math.h>

#define N 512
#define H 12
#define CC 16      // C
#define CZ 128
#define CS 384
#define PQ 4
#define PV 8
#define CATR 2017

// ---------------------------------------------------------------------------
// Kernel 1: all projections. out[o,n] = sum_c W_sel[o][c] * s[c,n], o in [0,1152)
// ---------------------------------------------------------------------------
__global__ __launch_bounds__(256) void k_proj(
    const float* __restrict__ s,
    const float* __restrict__ Wq, const float* __restrict__ Wk, const float* __restrict__ Wv,
    const float* __restrict__ Wqp, const float* __restrict__ Wkp, const float* __restrict__ Wvp,
    float* __restrict__ proj)
{
    __shared__ float Wt[16][33];
    __shared__ float St[32][128];
    int t = threadIdx.x;
    int o0 = blockIdx.x * 16;
    int n0 = blockIdx.y * 128;
    const float* Wsrc; int orow;
    if (o0 < 192)      { Wsrc = Wq;  orow = o0; }
    else if (o0 < 384) { Wsrc = Wk;  orow = o0-192; }
    else if (o0 < 576) { Wsrc = Wv;  orow = o0-384; }
    else if (o0 < 720) { Wsrc = Wqp; orow = o0-576; }
    else if (o0 < 864) { Wsrc = Wkp; orow = o0-720; }
    else               { Wsrc = Wvp; orow = o0-864; }

    int og = t >> 6, nl = t & 63;
    float acc[4][2] = {};
    for (int c0 = 0; c0 < CS; c0 += 32) {
        __syncthreads();
        for (int k = 0; k < 2; k++) {
            int idx = t + k*256;
            int oo = idx >> 5, ccol = idx & 31;
            Wt[oo][ccol] = Wsrc[(orow+oo)*CS + c0 + ccol];
        }
        for (int k = 0; k < 4; k++) {
            int idx = t + k*256;
            int ccr = idx >> 5, nn4 = idx & 31;
            float4 v = *(const float4*)&s[(c0+ccr)*N + n0 + nn4*4];
            *(float4*)&St[ccr][nn4*4] = v;
        }
        __syncthreads();
        for (int kk = 0; kk < 32; kk++) {
            float sv0 = St[kk][nl], sv1 = St[kk][nl+64];
            #pragma unroll
            for (int r = 0; r < 4; r++) {
                float w = Wt[og*4+r][kk];
                acc[r][0] += w * sv0;
                acc[r][1] += w * sv1;
            }
        }
    }
    for (int r = 0; r < 4; r++) {
        int o = o0 + og*4 + r;
        proj[o*N + n0 + nl]      = acc[r][0];
        proj[o*N + n0 + 64 + nl] = acc[r][1];
    }
}

// ---------------------------------------------------------------------------
// Kernel 2: apply frames.
// ---------------------------------------------------------------------------
__global__ void k_frames(const float* __restrict__ proj,
                         const float* __restrict__ t_r, const float* __restrict__ t_t,
                         float* __restrict__ qg, float* __restrict__ kg, float* __restrict__ vg)
{
    int gid = blockIdx.x * blockDim.x + threadIdx.x;
    int n = gid & (N-1);
    int hp = gid >> 9;
    if (hp >= 192) return;
    const float* src; float* dst; int rowb, stride;
    if (hp < 48)      { src = proj + 576*N; dst = qg; rowb = hp;    stride = 48; }
    else if (hp < 96) { src = proj + 720*N; dst = kg; rowb = hp-48; stride = 48; }
    else              { src = proj + 864*N; dst = vg; rowb = hp-96; stride = 96; }
    float x0 = src[(rowb + 0*stride)*N + n];
    float x1 = src[(rowb + 1*stride)*N + n];
    float x2 = src[(rowb + 2*stride)*N + n];
    #pragma unroll
    for (int d = 0; d < 3; d++) {
        float r0 = t_r[(n*3+d)*3+0], r1 = t_r[(n*3+d)*3+1], r2 = t_r[(n*3+d)*3+2];
        dst[(rowb + d*stride)*N + n] = r0*x0 + r1*x1 + r2*x2 + t_t[n*3+d];
    }
}

// ---------------------------------------------------------------------------
// Kernel 2b: squared norms per (h,n).
// ---------------------------------------------------------------------------
__global__ void k_sq(const float* __restrict__ qg, const float* __restrict__ kg,
                     float* __restrict__ sq_q, float* __restrict__ sq_k)
{
    int gid = blockIdx.x * blockDim.x + threadIdx.x;
    int n = gid & (N-1);
    int sel = gid >> 9;
    int h = sel % H;
    const float* g = (sel < H) ? qg : kg;
    float* outp = (sel < H) ? sq_q : sq_k;
    float acc = 0.f;
    #pragma unroll
    for (int d = 0; d < 3; d++)
        #pragma unroll
        for (int p = 0; p < PQ; p++) {
            float v = g[(size_t)((d*H + h)*PQ + p)*N + n];
            acc += v*v;
        }
    outp[h*N + n] = acc;
}

// ---------------------------------------------------------------------------
// Kernel 3: logits + softmax. block per i. 256 threads:
//   half = t>>7 (wave-uniform c-split), jl = t&127, j4 = jl*4 (float4 over j).
// ---------------------------------------------------------------------------
__global__ __launch_bounds__(256) void k_attn(
    const float* __restrict__ z, const float* __restrict__ proj,
    const float* __restrict__ qg, const float* __restrict__ kg,
    const float* __restrict__ sq_q, const float* __restrict__ sq_k,
    const float* __restrict__ Wb, const float* __restrict__ gamma,
    float* __restrict__ a)
{
    __shared__ float redbuf[128*52];     // 26.6 KB cross-half reduction
    __shared__ float sred[2][H][2];
    int i = blockIdx.x;
    int t = threadIdx.x;
    int half = t >> 7;                   // wave-uniform
    int jl = t & 127;
    int j4 = jl * 4;
    const float w_l  = 0.57735026918962584f;   // sqrt(1/3)
    const float w_c2 = 0.11785113019775793f;   // sqrt(1/18)/2

    float ch[H];
    #pragma unroll
    for (int h = 0; h < H; h++) {
        float g = gamma[h];
        float sp = (g > 20.f) ? g : log1pf(expf(g));
        ch[h] = sp * w_c2;
    }

    float acc[H][4] = {};

    // ---- b_bias: 64 c per half, unroll 4 (4 KB in flight per wave)
    {
        const float* zi = z + (size_t)i * N;
        int cbeg = half * 64;
        for (int c = cbeg; c < cbeg + 64; c += 4) {
            float4 z0 = *(const float4*)&zi[(size_t)(c+0)*N*N + j4];
            float4 z1 = *(const float4*)&zi[(size_t)(c+1)*N*N + j4];
            float4 z2 = *(const float4*)&zi[(size_t)(c+2)*N*N + j4];
            float4 z3 = *(const float4*)&zi[(size_t)(c+3)*N*N + j4];
            #pragma unroll
            for (int h = 0; h < H; h++) {
                float w0 = Wb[h*CZ + c+0], w1 = Wb[h*CZ + c+1];
                float w2 = Wb[h*CZ + c+2], w3 = Wb[h*CZ + c+3];
                acc[h][0] += w0*z0.x + w1*z1.x + w2*z2.x + w3*z3.x;
                acc[h][1] += w0*z0.y + w1*z1.y + w2*z2.y + w3*z3.y;
                acc[h][2] += w0*z0.z + w1*z1.z + w2*z2.z + w3*z3.z;
                acc[h][3] += w0*z0.w + w1*z1.w + w2*z2.w + w3*z3.w;
            }
        }
    }

    // ---- qk/4: rows c*12+h, 8 c per half
    {
        const float* q = proj;
        const float* k = proj + 192*N;
        for (int c = half*8; c < half*8 + 8; c++) {
            #pragma unroll
            for (int h = 0; h < H; h++) {
                int r = c*H + h;
                float qv = 0.25f * q[(size_t)r*N + i];
                float4 k4 = *(const float4*)&k[(size_t)r*N + j4];
                acc[h][0] += qv*k4.x; acc[h][1] += qv*k4.y;
                acc[h][2] += qv*k4.z; acc[h][3] += qv*k4.w;
            }
        }
    }

    // ---- +2*ch*(qg.kg): 12 (d,p) pairs, alternate by half
    {
        for (int dp = half; dp < 12; dp += 2) {
            int d = dp >> 2, p = dp & 3;
            #pragma unroll
            for (int h = 0; h < H; h++) {
                int r = (d*H + h)*PQ + p;
                float qv = 2.f * ch[h] * qg[(size_t)r*N + i];
                float4 k4 = *(const float4*)&kg[(size_t)r*N + j4];
                acc[h][0] += qv*k4.x; acc[h][1] += qv*k4.y;
                acc[h][2] += qv*k4.z; acc[h][3] += qv*k4.w;
            }
        }
    }

    // ---- cross-half reduction through LDS
    if (half == 1) {
        #pragma unroll
        for (int h = 0; h < H; h++)
            *(float4*)&redbuf[jl*52 + h*4] = *(float4*)&acc[h][0];
    }
    __syncthreads();
    if (half == 0) {
        #pragma unroll
        for (int h = 0; h < H; h++) {
            float4 o = *(const float4*)&redbuf[jl*52 + h*4];
            acc[h][0] += o.x; acc[h][1] += o.y; acc[h][2] += o.z; acc[h][3] += o.w;
        }
        // logits
        #pragma unroll
        for (int h = 0; h < H; h++) {
            float s0 = sq_q[h*N + i];
            float4 sk = *(const float4*)&sq_k[h*N + j4];
            acc[h][0] = w_l*(acc[h][0] - ch[h]*(s0 + sk.x));
            acc[h][1] = w_l*(acc[h][1] - ch[h]*(s0 + sk.y));
            acc[h][2] = w_l*(acc[h][2] - ch[h]*(s0 + sk.z));
            acc[h][3] = w_l*(acc[h][3] - ch[h]*(s0 + sk.w));
        }
        int wv = t >> 6, lane = t & 63;
        #pragma unroll
        for (int h = 0; h < H; h++) {
            float m = fmaxf(fmaxf(acc[h][0], acc[h][1]), fmaxf(acc[h][2], acc[h][3]));
            for (int s = 32; s > 0; s >>= 1) m = fmaxf(m, __shfl_xor(m, s));
            if (lane == 0) sred[0][h][wv] = m;
        }
    }
    __syncthreads();
    if (half == 0) {
        int wv = t >> 6, lane = t & 63;
        #pragma unroll
        for (int h = 0; h < H; h++) {
            float m = fmaxf(sred[0][h][0], sred[0][h][1]);
            acc[h][0] = __expf(acc[h][0]-m); acc[h][1] = __expf(acc[h][1]-m);
            acc[h][2] = __expf(acc[h][2]-m); acc[h][3] = __expf(acc[h][3]-m);
            float sm = acc[h][0]+acc[h][1]+acc[h][2]+acc[h][3];
            for (int s = 32; s > 0; s >>= 1) sm += __shfl_xor(sm, s);
            if (lane == 0) sred[1][h][wv] = sm;
        }
    }
    __syncthreads();
    if (half == 0) {
        #pragma unroll
        for (int h = 0; h < H; h++) {
            float inv = 1.f / (sred[1][h][0] + sred[1][h][1]);
            float4 o;
            o.x = acc[h][0]*inv; o.y = acc[h][1]*inv;
            o.z = acc[h][2]*inv; o.w = acc[h][3]*inv;
            *(float4*)&a[((size_t)h*N + i)*N + j4] = o;
        }
    }
}

// ---------------------------------------------------------------------------
// Kernel 4: o1[(c,h),i] = sum_j a[h,i,j]*z[c,i,j]. block per i.
// thread = (jh<<7)|(hg<<5)|cg : 4c (strided 32) x 3h accumulators, j-half split.
// All inner LDS traffic via ds_read_b128.
// ---------------------------------------------------------------------------
__global__ __launch_bounds__(256) void k_o1(
    const float* __restrict__ z, const float* __restrict__ a, float* __restrict__ cat)
{
    __shared__ float als[H*516];      // 24.8 KB
    __shared__ float zls[128*68];     // 34.8 KB
    int i = blockIdx.x;
    int t = threadIdx.x;
    int cg = t & 31, hg = (t>>5)&3, jh = t>>7;

    for (int k = 0; k < 6; k++) {     // stage a: 12x512, float4
        int idx = t + k*256;
        int h = idx >> 7, jj4 = idx & 127;
        *(float4*)&als[h*516 + jj4*4] = *(const float4*)&a[((size_t)h*N + i)*N + jj4*4];
    }
    float acc[4][3] = {};
    for (int jc = 0; jc < 8; jc++) {
        __syncthreads();
        for (int k = 0; k < 8; k++) { // stage z chunk 128x64, float4
            int idx = t + k*256;
            int c = idx >> 4, j4 = idx & 15;
            *(float4*)&zls[c*68 + j4*4] =
                *(const float4*)&z[((size_t)c*N + i)*N + jc*64 + j4*4];
        }
        __syncthreads();
        int jb = jh * 32;
        #pragma unroll
        for (int s = 0; s < 8; s++) {
            int jo = jb + s*4;
            float4 a0 = *(const float4*)&als[(hg*3+0)*516 + jc*64 + jo];
            float4 a1 = *(const float4*)&als[(hg*3+1)*516 + jc*64 + jo];
            float4 a2 = *(const float4*)&als[(hg*3+2)*516 + jc*64 + jo];
            #pragma unroll
            for (int r = 0; r < 4; r++) {
                float4 zz = *(const float4*)&zls[(cg + 32*r)*68 + jo];
                acc[r][0] += zz.x*a0.x + zz.y*a0.y + zz.z*a0.z + zz.w*a0.w;
                acc[r][1] += zz.x*a1.x + zz.y*a1.y + zz.z*a1.z + zz.w*a1.w;
                acc[r][2] += zz.x*a2.x + zz.y*a2.y + zz.z*a2.z + zz.w*a2.w;
            }
        }
    }
    __syncthreads();
    if (jh == 1) {
        float* rb = zls + (t & 127)*13;
        #pragma unroll
        for (int r = 0; r < 4; r++)
            #pragma unroll
            for (int hh = 0; hh < 3; hh++) rb[r*3+hh] = acc[r][hh];
    }
    __syncthreads();
    if (jh == 0) {
        const float* rb = zls + t*13;
        #pragma unroll
        for (int r = 0; r < 4; r++)
            #pragma unroll
            for (int hh = 0; hh < 3; hh++) acc[r][hh] += rb[r*3+hh];
        #pragma unroll
        for (int r = 0; r < 4; r++)
            #pragma unroll
            for (int hh = 0; hh < 3; hh++) {
                int c = cg + 32*r, h = hg*3 + hh;
                cat[(size_t)(c*H + h)*N + i] = acc[r][hh];
            }
    }
}

// ---------------------------------------------------------------------------
// Kernel 5: o2 + o3g. grid (12, 32): h x i-tile(16). j-half split.
// thread = (jh<<7)|(rg<<4)|il : 5 rows per rg, float4 inner.
// ---------------------------------------------------------------------------
__global__ __launch_bounds__(256) void k_o2o3g(
    const float* __restrict__ a, const float* __restrict__ proj, const float* __restrict__ vg,
    float* __restrict__ cat, float* __restrict__ o3g)
{
    __shared__ float ats[16*132];     // 8.4 KB
    __shared__ float vts[40*132];     // 21.1 KB
    int h = blockIdx.x, i0 = blockIdx.y*16;
    int t = threadIdx.x;
    int il = t & 15, rg = (t>>4)&7, jh = t>>7;
    const float* v = proj + 384*N;
    float acc[5] = {};
    for (int jc = 0; jc < 4; jc++) {
        __syncthreads();
        for (int k = 0; k < 2; k++) {  // a tile 16x128 float4
            int idx = t + k*256;
            int ii = idx >> 5, j4 = idx & 31;
            *(float4*)&ats[ii*132 + j4*4] =
                *(const float4*)&a[((size_t)h*N + i0+ii)*N + jc*128 + j4*4];
        }
        for (int idx = t; idx < 1280; idx += 256) {  // v/vg tile 40x128 float4
            int r = idx >> 5, j4 = idx & 31;
            const float* src = (r < 16) ? (v + (size_t)(r*H + h)*N)
                : (vg + (size_t)(((r-16)>>3)*96 + h*PV + ((r-16)&7))*N);
            *(float4*)&vts[r*132 + j4*4] = *(const float4*)&src[jc*128 + j4*4];
        }
        __syncthreads();
        int jb = jh * 64;
        #pragma unroll
        for (int s = 0; s < 16; s++) {
            int jo = jb + s*4;
            float4 a4 = *(const float4*)&ats[il*132 + jo];
            #pragma unroll
            for (int r = 0; r < 5; r++) {
                float4 v4 = *(const float4*)&vts[(rg*5+r)*132 + jo];
                acc[r] += v4.x*a4.x + v4.y*a4.y + v4.z*a4.z + v4.w*a4.w;
            }
        }
    }
    __syncthreads();
    if (jh == 1) {
        float* rb = ats + (t & 127)*6;
        #pragma unroll
        for (int r = 0; r < 5; r++) rb[r] = acc[r];
    }
    __syncthreads();
    if (jh == 0) {
        const float* rb = ats + t*6;
        #pragma unroll
        for (int r = 0; r < 5; r++) acc[r] += rb[r];
        #pragma unroll
        for (int r = 0; r < 5; r++) {
            int row = rg*5 + r;
            if (row < 16) cat[(size_t)(1536 + row*H + h)*N + i0 + il] = acc[r];
            else { int rr = row - 16;
                   o3g[(size_t)((rr>>3)*96 + h*PV + (rr&7))*N + i0 + il] = acc[r]; }
        }
    }
}

// ---------------------------------------------------------------------------
// Kernel 6: inverse frame transform -> cat rows 1728..2015
// ---------------------------------------------------------------------------
__global__ void k_o3(const float* __restrict__ o3g,
                     const float* __restrict__ t_r, const float* __restrict__ t_t,
                     float* __restrict__ cat)
{
    int gid = blockIdx.x*blockDim.x + threadIdx.x;
    int i = gid & (N-1), hp = gid >> 9;
    if (hp >= 96) return;
    float x0 = o3g[(size_t)(0*96 + hp)*N + i] - t_t[i*3+0];
    float x1 = o3g[(size_t)(1*96 + hp)*N + i] - t_t[i*3+1];
    float x2 = o3g[(size_t)(2*96 + hp)*N + i] - t_t[i*3+2];
    #pragma unroll
    for (int d = 0; d < 3; d++) {
        float o = t_r[(i*3+0)*3+d]*x0 + t_r[(i*3+1)*3+d]*x1 + t_r[(i*3+2)*3+d]*x2;
        cat[(size_t)(1728 + d*96 + hp)*N + i] = o;
    }
}

// ---------------------------------------------------------------------------
// Kernel 6b: o3_norm -> cat row 2016
// ---------------------------------------------------------------------------
__global__ void k_norm(float* __restrict__ cat)
{
    int i = blockIdx.x*blockDim.x + threadIdx.x;
    if (i >= N) return;
    float acc = 0.f;
    for (int r = 0; r < 288; r++) {
        float v = cat[(size_t)(1728+r)*N + i];
        acc += v*v;
    }
    cat[(size_t)2016*N + i] = sqrtf(acc);
}

// ---------------------------------------------------------------------------
// Kernel 7: final GEMM, split-K=4 with atomics.
// ---------------------------------------------------------------------------
__global__ __launch_bounds__(256) void k_final(
    const float* __restrict__ Ws, const float* __restrict__ bs,
    const float* __restrict__ cat, float* __restrict__ out)
{
    __shared__ float Wt[16*33];
    __shared__ float Ct[32*66];
    int o0 = blockIdx.x*16, n0 = blockIdx.y*64;
    int ks = blockIdx.z;
    int kbeg = ks*505, kend = min(CATR, kbeg+505);
    int t = threadIdx.x;
    int og = t >> 6, nl = t & 63;
    float acc[4] = {};
    for (int c0 = kbeg; c0 < kend; c0 += 32) {
        __syncthreads();
        for (int k = 0; k < 2; k++) {
            int idx = t + k*256;
            int oo = idx >> 5, ccol = idx & 31;
            int c = c0 + ccol;
            Wt[oo*33 + ccol] = (c < kend) ? Ws[(size_t)(o0+oo)*CATR + c] : 0.f;
        }
        for (int k = 0; k < 4; k++) {
            int idx = t + k*256;
            int ccr = idx >> 5, j2 = idx & 31;
            int c = c0 + ccr;
            float2 vv; vv.x = 0.f; vv.y = 0.f;
            if (c < kend) vv = *(const float2*)&cat[(size_t)c*N + n0 + j2*2];
            *(float2*)&Ct[ccr*66 + j2*2] = vv;
        }
        __syncthreads();
        int klim = min(32, kend - c0);
        for (int kk = 0; kk < klim; kk++) {
            float cv = Ct[kk*66 + nl];
            #pragma unroll
            for (int r = 0; r < 4; r++)
                acc[r] += Wt[(og*4+r)*33 + kk] * cv;
        }
    }
    #pragma unroll
    for (int r = 0; r < 4; r++) {
        int o = o0 + og*4 + r;
        float val = acc[r];
        if (ks == 0) val += bs[o];
        atomicAdd(&out[(size_t)o*N + n0 + nl], val);
    }
}

// ---------------------------------------------------------------------------
extern "C" void kernel_launch(void* const* d_in, const int* in_sizes, int n_in,
                              void* d_out, int out_size, void* d_ws, size_t ws_size,
                              hipStream_t stream)
{
    const float* s     = (const float*)d_in[0];
    const float* z     = (const float*)d_in[1];
    const float* t_r   = (const float*)d_in[2];
    const float* t_t   = (const float*)d_in[3];
    const float* Wq    = (const float*)d_in[4];
    const float* Wk    = (const float*)d_in[5];
    const float* Wv    = (const float*)d_in[6];
    const float* Wqp   = (const float*)d_in[7];
    const float* Wkp   = (const float*)d_in[8];
    const float* Wvp   = (const float*)d_in[9];
    const float* Wb    = (const float*)d_in[10];
    const float* gamma = (const float*)d_in[11];
    const float* Ws    = (const float*)d_in[12];
    const float* bs    = (const float*)d_in[13];
    float* out = (float*)d_out;

    float* ws   = (float*)d_ws;
    float* proj = ws;                       // 1152*512
    float* qg   = proj + 1152*N;            // 144*512
    float* kg   = qg   + 144*N;             // 144*512
    float* vg   = kg   + 144*N;             // 288*512
    float* sq_q = vg   + 288*N;             // 12*512
    float* sq_k = sq_q + H*N;               // 12*512
    float* o3g  = sq_k + H*N;               // 288*512
    float* a    = o3g  + 288*N;             // 12*512*512
    float* cat  = a    + (size_t)H*N*N;     // 2017*512

    k_proj  <<<dim3(72,4),  256, 0, stream>>>(s, Wq, Wk, Wv, Wqp, Wkp, Wvp, proj);
    k_frames<<<384,         256, 0, stream>>>(proj, t_r, t_t, qg, kg, vg);
    k_sq    <<<48,          256, 0, stream>>>(qg, kg, sq_q, sq_k);
    k_attn  <<<512,         256, 0, stream>>>(z, proj, qg, kg, sq_q, sq_k, Wb, gamma, a);
    k_o1    <<<512,         256, 0, stream>>>(z, a, cat);
    k_o2o3g <<<dim3(12,32), 256, 0, stream>>>(a, proj, vg, cat, o3g);
    k_o3    <<<192,         256, 0, stream>>>(o3g, t_r, t_t, cat);
    k_norm  <<<2,           256, 0, stream>>>(cat);
    hipMemsetAsync(out, 0, (size_t)CS*N*sizeof(float), stream);
    k_final <<<dim3(24,8,4),256, 0, stream>>>(Ws, bs, cat, out);
}